// Round 1
// baseline (145.702 us; speedup 1.0000x reference)
//
#include <hip/hip_runtime.h>
#include <math.h>

#define LOG2E 1.4426950408889634f
#define LN2   0.6931471805599453f

// Kernel A: per-component coefficient precompute + d_out zero-init.
// For component j with precision matrix G = [[g11,g12],[g12,g22]]:
//   qf(sx,sy) = A*sx^2 + B*sx*sy + C*sy^2 + D*sx + E*sy + F
// exponent (base-2) = K2 - A2*xx - B2*xy - C2*yy - D2*sx - E2*sy
// params[2j]   = {A2, B2, C2, D2}
// params[2j+1] = {E2, K2, 0, 0}
__global__ __launch_bounds__(1024) void gm_params(
    const float* __restrict__ mu,         // (M,2)
    const float* __restrict__ sigma_log,  // (M,2)
    const float* __restrict__ theta,      // (M,)
    const float* __restrict__ w,          // (M,1)
    float4* __restrict__ params,          // (2M,)
    float* __restrict__ out)
{
    __shared__ float red[1024];
    const int j = threadIdx.x;

    float wj = w[j];

    // log-softmax denominator: logsumexp over w (w ~ N(0,1): exp is safe raw)
    red[j] = __expf(wj);
    __syncthreads();
    for (int s = 512; s > 0; s >>= 1) {
        if (j < s) red[j] += red[j + s];
        __syncthreads();
    }
    const float lse = __logf(red[0]);

    const float sl0 = sigma_log[2 * j + 0];
    const float sl1 = sigma_log[2 * j + 1];
    const float a = __expf(-2.0f * sl0);
    const float b = __expf(-2.0f * sl1);
    const float th = theta[j];
    const float c = cosf(th);
    const float s = sinf(th);

    const float g11 = a * c * c + b * s * s;
    const float g12 = (a - b) * c * s;
    const float g22 = a * s * s + b * c * c;

    const float mx = mu[2 * j + 0];
    const float my = mu[2 * j + 1];

    const float wlog = wj - lse - (sl0 + sl1);

    const float A = g11;
    const float B = 2.0f * g12;
    const float C = g22;
    const float D = -(2.0f * g11 * mx + 2.0f * g12 * my);
    const float E = -(2.0f * g12 * mx + 2.0f * g22 * my);
    const float F = g11 * mx * mx + 2.0f * g12 * mx * my + g22 * my * my;
    const float K = (wlog - F) * LOG2E;

    params[2 * j + 0] = make_float4(A * LOG2E, B * LOG2E, C * LOG2E, D * LOG2E);
    params[2 * j + 1] = make_float4(E * LOG2E, K, 0.0f, 0.0f);

    if (j == 0) out[0] = 0.0f;
}

// Kernel B: one thread per sample, loop over all M components.
__global__ __launch_bounds__(256) void gm_main(
    const float* __restrict__ sample,   // (N,2)
    const float4* __restrict__ params,  // (2M,)
    float* __restrict__ out,
    int N, int M)
{
    const int i = blockIdx.x * blockDim.x + threadIdx.x;
    const int ii = (i < N) ? i : 0;

    const float2 sv = ((const float2*)sample)[ii];
    const float sx = sv.x, sy = sv.y;
    const float xx = sx * sx;
    const float xy = sx * sy;
    const float yy = sy * sy;

    float acc0 = 0.0f, acc1 = 0.0f, acc2 = 0.0f, acc3 = 0.0f;

    for (int j = 0; j < M; j += 4) {
        {
            const float4 p = params[2 * (j + 0) + 0];
            const float4 q = params[2 * (j + 0) + 1];
            float e = fmaf(-p.x, xx, fmaf(-p.y, xy, fmaf(-p.z, yy,
                      fmaf(-p.w, sx, fmaf(-q.x, sy, q.y)))));
            acc0 += __builtin_amdgcn_exp2f(e);
        }
        {
            const float4 p = params[2 * (j + 1) + 0];
            const float4 q = params[2 * (j + 1) + 1];
            float e = fmaf(-p.x, xx, fmaf(-p.y, xy, fmaf(-p.z, yy,
                      fmaf(-p.w, sx, fmaf(-q.x, sy, q.y)))));
            acc1 += __builtin_amdgcn_exp2f(e);
        }
        {
            const float4 p = params[2 * (j + 2) + 0];
            const float4 q = params[2 * (j + 2) + 1];
            float e = fmaf(-p.x, xx, fmaf(-p.y, xy, fmaf(-p.z, yy,
                      fmaf(-p.w, sx, fmaf(-q.x, sy, q.y)))));
            acc2 += __builtin_amdgcn_exp2f(e);
        }
        {
            const float4 p = params[2 * (j + 3) + 0];
            const float4 q = params[2 * (j + 3) + 1];
            float e = fmaf(-p.x, xx, fmaf(-p.y, xy, fmaf(-p.z, yy,
                      fmaf(-p.w, sx, fmaf(-q.x, sy, q.y)))));
            acc3 += __builtin_amdgcn_exp2f(e);
        }
    }

    const float accs = (acc0 + acc1) + (acc2 + acc3);
    // ll_i = ln(sum) ; contribute -ll_i
    float v = -LN2 * __builtin_amdgcn_logf(accs);
    if (i >= N) v = 0.0f;

    // wave (64-lane) reduction
    for (int off = 32; off > 0; off >>= 1)
        v += __shfl_down(v, off, 64);

    __shared__ float wsum[4];
    const int lane = threadIdx.x & 63;
    const int wid  = threadIdx.x >> 6;
    if (lane == 0) wsum[wid] = v;
    __syncthreads();
    if (threadIdx.x == 0) {
        atomicAdd(out, (wsum[0] + wsum[1]) + (wsum[2] + wsum[3]));
    }
}

extern "C" void kernel_launch(void* const* d_in, const int* in_sizes, int n_in,
                              void* d_out, int out_size, void* d_ws, size_t ws_size,
                              hipStream_t stream) {
    const float* sample    = (const float*)d_in[0];
    const float* mu        = (const float*)d_in[1];
    const float* sigma_log = (const float*)d_in[2];
    const float* theta     = (const float*)d_in[3];
    const float* w         = (const float*)d_in[4];
    float* out = (float*)d_out;
    float4* params = (float4*)d_ws;

    const int M = in_sizes[3];      // 1024
    const int N = in_sizes[0] / 2;  // 65536

    gm_params<<<1, M, 0, stream>>>(mu, sigma_log, theta, w, params, out);

    const int block = 256;
    const int grid = (N + block - 1) / block;  // 256
    gm_main<<<grid, block, 0, stream>>>(sample, params, out, N, M);
}

// Round 2
// 124.135 us; speedup vs baseline: 1.1737x; 1.1737x over previous
//
#include <hip/hip_runtime.h>
#include <math.h>

#define LOG2E 1.4426950408889634f
#define LN2   0.6931471805599453f

// Kernel A: per-component coefficient precompute + d_out zero-init.
// exponent (base-2) for pair (i,j) = K2 - A2*xx - B2*xy - C2*yy - D2*sx - E2*sy
// params[2j]   = {A2, B2, C2, D2}
// params[2j+1] = {E2, K2, 0, 0}
__global__ __launch_bounds__(1024) void gm_params(
    const float* __restrict__ mu,         // (M,2)
    const float* __restrict__ sigma_log,  // (M,2)
    const float* __restrict__ theta,      // (M,)
    const float* __restrict__ w,          // (M,1)
    float4* __restrict__ params,          // (2M,)
    float* __restrict__ out)
{
    const int j = threadIdx.x;
    const int lane = j & 63;
    const int wid  = j >> 6;

    const float wj = w[j];

    // logsumexp over w (w ~ N(0,1): raw exp is safe)
    float e = __expf(wj);
    #pragma unroll
    for (int off = 32; off > 0; off >>= 1)
        e += __shfl_down(e, off, 64);

    __shared__ float ws[16];
    if (lane == 0) ws[wid] = e;
    __syncthreads();

    float tot = 0.0f;
    #pragma unroll
    for (int k = 0; k < 16; ++k) tot += ws[k];
    const float lse = __logf(tot);

    const float sl0 = sigma_log[2 * j + 0];
    const float sl1 = sigma_log[2 * j + 1];
    const float a = __expf(-2.0f * sl0);
    const float b = __expf(-2.0f * sl1);
    const float th = theta[j];
    const float c = __cosf(th);
    const float s = __sinf(th);

    const float g11 = a * c * c + b * s * s;
    const float g12 = (a - b) * c * s;
    const float g22 = a * s * s + b * c * c;

    const float mx = mu[2 * j + 0];
    const float my = mu[2 * j + 1];

    const float wlog = wj - lse - (sl0 + sl1);

    const float A = g11;
    const float B = 2.0f * g12;
    const float C = g22;
    const float D = -(2.0f * g11 * mx + 2.0f * g12 * my);
    const float E = -(2.0f * g12 * mx + 2.0f * g22 * my);
    const float F = g11 * mx * mx + 2.0f * g12 * mx * my + g22 * my * my;
    const float K = (wlog - F) * LOG2E;

    params[2 * j + 0] = make_float4(A * LOG2E, B * LOG2E, C * LOG2E, D * LOG2E);
    params[2 * j + 1] = make_float4(E * LOG2E, K, 0.0f, 0.0f);

    if (j == 0) out[0] = 0.0f;
}

// Kernel B: block = 64 samples x 4 M-chunks. Each thread sums exp terms for
// one sample over M/4 components; LDS combines the 4 partials per sample;
// wave 0 does log + reduction + one atomic per block.
__global__ __launch_bounds__(256) void gm_main(
    const float* __restrict__ sample,   // (N,2)
    const float4* __restrict__ params,  // (2M,)
    float* __restrict__ out,
    int M)
{
    const int lane_s = threadIdx.x & 63;   // sample within block
    const int chunk  = threadIdx.x >> 6;   // M-chunk [0,4)
    const int i = blockIdx.x * 64 + lane_s;

    const float2 sv = ((const float2*)sample)[i];
    const float sx = sv.x, sy = sv.y;
    const float xx = sx * sx;
    const float xy = sx * sy;
    const float yy = sy * sy;

    const int mq = M >> 2;                 // 256
    const int j0 = chunk * mq;
    const int j1 = j0 + mq;

    float acc[8];
    #pragma unroll
    for (int u = 0; u < 8; ++u) acc[u] = 0.0f;

    for (int j = j0; j < j1; j += 8) {
        #pragma unroll
        for (int u = 0; u < 8; ++u) {
            const float4 p = params[2 * (j + u) + 0];
            const float4 q = params[2 * (j + u) + 1];
            const float ev = fmaf(-p.x, xx, fmaf(-p.y, xy, fmaf(-p.z, yy,
                             fmaf(-p.w, sx, fmaf(-q.x, sy, q.y)))));
            acc[u] += __builtin_amdgcn_exp2f(ev);
        }
    }

    const float accs = ((acc[0] + acc[1]) + (acc[2] + acc[3]))
                     + ((acc[4] + acc[5]) + (acc[6] + acc[7]));

    __shared__ float psum[4][64];
    psum[chunk][lane_s] = accs;
    __syncthreads();

    if (threadIdx.x < 64) {
        const float tot = (psum[0][lane_s] + psum[1][lane_s])
                        + (psum[2][lane_s] + psum[3][lane_s]);
        float v = -LN2 * __builtin_amdgcn_logf(tot);
        #pragma unroll
        for (int off = 32; off > 0; off >>= 1)
            v += __shfl_down(v, off, 64);
        if (lane_s == 0) atomicAdd(out, v);
    }
}

extern "C" void kernel_launch(void* const* d_in, const int* in_sizes, int n_in,
                              void* d_out, int out_size, void* d_ws, size_t ws_size,
                              hipStream_t stream) {
    const float* sample    = (const float*)d_in[0];
    const float* mu        = (const float*)d_in[1];
    const float* sigma_log = (const float*)d_in[2];
    const float* theta     = (const float*)d_in[3];
    const float* w         = (const float*)d_in[4];
    float* out = (float*)d_out;
    float4* params = (float4*)d_ws;

    const int M = in_sizes[3];      // 1024
    const int N = in_sizes[0] / 2;  // 65536

    gm_params<<<1, M, 0, stream>>>(mu, sigma_log, theta, w, params, out);

    const int grid = N / 64;        // 1024 blocks, 256 threads each
    gm_main<<<grid, 256, 0, stream>>>(sample, params, out, M);
}

// Round 4
// 94.840 us; speedup vs baseline: 1.5363x; 1.3089x over previous
//
#include <hip/hip_runtime.h>
#include <math.h>

#define LOG2E 1.4426950408889634f
#define LN2   0.6931471805599453f

// Kernel A: per-component coefficient precompute + d_out zero-init.
// exponent (base-2) for pair (i,j) = K2 - A2*xx - B2*xy - C2*yy - D2*sx - E2*sy
// params[2j]   = {A2, B2, C2, D2}
// params[2j+1] = {E2, K2, 0, 0}
__global__ __launch_bounds__(1024) void gm_params(
    const float* __restrict__ mu,         // (M,2)
    const float* __restrict__ sigma_log,  // (M,2)
    const float* __restrict__ theta,      // (M,)
    const float* __restrict__ w,          // (M,1)
    float4* __restrict__ params,          // (2M,)
    float* __restrict__ out)
{
    const int j = threadIdx.x;
    const int lane = j & 63;
    const int wid  = j >> 6;

    const float wj = w[j];

    // logsumexp over w (w ~ N(0,1): raw exp is safe)
    float e = __expf(wj);
    #pragma unroll
    for (int off = 32; off > 0; off >>= 1)
        e += __shfl_down(e, off, 64);

    __shared__ float ws[16];
    if (lane == 0) ws[wid] = e;
    __syncthreads();

    float tot = 0.0f;
    #pragma unroll
    for (int k = 0; k < 16; ++k) tot += ws[k];
    const float lse = __logf(tot);

    const float sl0 = sigma_log[2 * j + 0];
    const float sl1 = sigma_log[2 * j + 1];
    const float a = __expf(-2.0f * sl0);
    const float b = __expf(-2.0f * sl1);
    const float th = theta[j];
    const float c = __cosf(th);
    const float s = __sinf(th);

    const float g11 = a * c * c + b * s * s;
    const float g12 = (a - b) * c * s;
    const float g22 = a * s * s + b * c * c;

    const float mx = mu[2 * j + 0];
    const float my = mu[2 * j + 1];

    const float wlog = wj - lse - (sl0 + sl1);

    const float A = g11;
    const float B = 2.0f * g12;
    const float C = g22;
    const float D = -(2.0f * g11 * mx + 2.0f * g12 * my);
    const float E = -(2.0f * g12 * mx + 2.0f * g22 * my);
    const float F = g11 * mx * mx + 2.0f * g12 * mx * my + g22 * my * my;
    const float K = (wlog - F) * LOG2E;

    params[2 * j + 0] = make_float4(A * LOG2E, B * LOG2E, C * LOG2E, D * LOG2E);
    params[2 * j + 1] = make_float4(E * LOG2E, K, 0.0f, 0.0f);

    if (j == 0) out[0] = 0.0f;
}

// Kernel B: block = 64 samples x 8 wave-uniform M-chunks (one chunk per wave).
// Param index is wave-uniform -> scalar (SMEM) loads; VALU sees only FMA+exp.
__global__ __launch_bounds__(512) void gm_main(
    const float* __restrict__ sample,   // (N,2)
    const float4* __restrict__ params,  // (2M,)
    float* __restrict__ out,
    int M)
{
    const int lane_s = threadIdx.x & 63;   // sample within block
    // Force wave-uniformity so the backend selects s_load for params.
    int chunk = __builtin_amdgcn_readfirstlane((int)(threadIdx.x >> 6)); // 0..7
    chunk &= 7;
    __builtin_assume(chunk >= 0 && chunk < 8);
    const int i = blockIdx.x * 64 + lane_s;

    const float2 sv = ((const float2*)sample)[i];
    const float sx = sv.x, sy = sv.y;
    const float xx = sx * sx;
    const float xy = sx * sy;
    const float yy = sy * sy;

    const int mq = M >> 3;                 // 128 components per wave
    const int j0 = chunk * mq;

    float acc[8];
    #pragma unroll
    for (int u = 0; u < 8; ++u) acc[u] = 0.0f;

    for (int jj = 0; jj < mq; jj += 8) {
        const int j = j0 + jj;
        #pragma unroll
        for (int u = 0; u < 8; ++u) {
            const float4 p = params[2 * (j + u) + 0];
            const float4 q = params[2 * (j + u) + 1];
            const float ev = fmaf(-p.x, xx, fmaf(-p.y, xy, fmaf(-p.z, yy,
                             fmaf(-p.w, sx, fmaf(-q.x, sy, q.y)))));
            acc[u] += __builtin_amdgcn_exp2f(ev);
        }
    }

    const float accs = ((acc[0] + acc[1]) + (acc[2] + acc[3]))
                     + ((acc[4] + acc[5]) + (acc[6] + acc[7]));

    __shared__ float psum[8][64];
    psum[chunk][lane_s] = accs;
    __syncthreads();

    if (threadIdx.x < 64) {
        const float tot = ((psum[0][lane_s] + psum[1][lane_s])
                        +  (psum[2][lane_s] + psum[3][lane_s]))
                        + ((psum[4][lane_s] + psum[5][lane_s])
                        +  (psum[6][lane_s] + psum[7][lane_s]));
        float v = -LN2 * __builtin_amdgcn_logf(tot);
        #pragma unroll
        for (int off = 32; off > 0; off >>= 1)
            v += __shfl_down(v, off, 64);
        if (lane_s == 0) atomicAdd(out, v);
    }
}

extern "C" void kernel_launch(void* const* d_in, const int* in_sizes, int n_in,
                              void* d_out, int out_size, void* d_ws, size_t ws_size,
                              hipStream_t stream) {
    const float* sample    = (const float*)d_in[0];
    const float* mu        = (const float*)d_in[1];
    const float* sigma_log = (const float*)d_in[2];
    const float* theta     = (const float*)d_in[3];
    const float* w         = (const float*)d_in[4];
    float* out = (float*)d_out;
    float4* params = (float4*)d_ws;

    const int M = in_sizes[3];      // 1024
    const int N = in_sizes[0] / 2;  // 65536

    gm_params<<<1, M, 0, stream>>>(mu, sigma_log, theta, w, params, out);

    const int grid = N / 64;        // 1024 blocks, 512 threads each
    gm_main<<<grid, 512, 0, stream>>>(sample, params, out, M);
}

// Round 5
// 81.747 us; speedup vs baseline: 1.7823x; 1.1602x over previous
//
#include <hip/hip_runtime.h>
#include <math.h>

#define LOG2E 1.4426950408889634f
#define LN2   0.6931471805599453f

typedef float v2f __attribute__((ext_vector_type(2)));

// Params layout: pairwise-AoS. For component pair p = (2p, 2p+1), record of
// 12 floats at pp[12p]: [A0,A1, B0,B1, C0,C1, D0,D1, E0,E1, K0,K1].
// All coefficients pre-scaled by LOG2E and pre-negated (except K) so the
// inner loop is pure fma-accumulate:
//   e2 = K + A*xx + B*xy + C*yy + D*sx + E*sy   (base-2 exponent)
__global__ __launch_bounds__(1024) void gm_params(
    const float* __restrict__ mu,         // (M,2)
    const float* __restrict__ sigma_log,  // (M,2)
    const float* __restrict__ theta,      // (M,)
    const float* __restrict__ w,          // (M,1)
    float* __restrict__ pp,               // (12*M/2,)
    float* __restrict__ out)
{
    const int j = threadIdx.x;
    const int lane = j & 63;
    const int wid  = j >> 6;

    const float wj = w[j];

    // logsumexp over w (w ~ N(0,1): raw exp is safe)
    float e = __expf(wj);
    #pragma unroll
    for (int off = 32; off > 0; off >>= 1)
        e += __shfl_down(e, off, 64);

    __shared__ float ws[16];
    if (lane == 0) ws[wid] = e;
    __syncthreads();

    float tot = 0.0f;
    #pragma unroll
    for (int k = 0; k < 16; ++k) tot += ws[k];
    const float lse = __logf(tot);

    const float sl0 = sigma_log[2 * j + 0];
    const float sl1 = sigma_log[2 * j + 1];
    const float a = __expf(-2.0f * sl0);
    const float b = __expf(-2.0f * sl1);
    const float th = theta[j];
    const float c = __cosf(th);
    const float s = __sinf(th);

    const float g11 = a * c * c + b * s * s;
    const float g12 = (a - b) * c * s;
    const float g22 = a * s * s + b * c * c;

    const float mx = mu[2 * j + 0];
    const float my = mu[2 * j + 1];

    const float wlog = wj - lse - (sl0 + sl1);

    const float A = g11;
    const float B = 2.0f * g12;
    const float C = g22;
    const float D = -(2.0f * g11 * mx + 2.0f * g12 * my);
    const float E = -(2.0f * g12 * mx + 2.0f * g22 * my);
    const float F = g11 * mx * mx + 2.0f * g12 * mx * my + g22 * my * my;
    const float K = (wlog - F) * LOG2E;

    const int base = 12 * (j >> 1) + (j & 1);
    pp[base + 0]  = -A * LOG2E;
    pp[base + 2]  = -B * LOG2E;
    pp[base + 4]  = -C * LOG2E;
    pp[base + 6]  = -D * LOG2E;
    pp[base + 8]  = -E * LOG2E;
    pp[base + 10] = K;

    if (j == 0) out[0] = 0.0f;
}

// Kernel B: block = 64 samples x 8 wave-uniform M-chunks (one chunk per wave).
// Wave-uniform param records -> scalar s_load; packed fp32 (v_pk_fma_f32)
// computes two components' exponents per instruction.
__global__ __launch_bounds__(512) void gm_main(
    const float* __restrict__ sample,   // (N,2)
    const float* __restrict__ pp,       // pairwise param records
    float* __restrict__ out,
    int M)
{
    const int lane_s = threadIdx.x & 63;   // sample within block
    int chunk = __builtin_amdgcn_readfirstlane((int)(threadIdx.x >> 6)); // 0..7
    chunk &= 7;
    __builtin_assume(chunk >= 0 && chunk < 8);
    const int i = blockIdx.x * 64 + lane_s;

    const float2 sv = ((const float2*)sample)[i];
    const float sx = sv.x, sy = sv.y;
    const v2f xx2 = (v2f)(sx * sx);
    const v2f xy2 = (v2f)(sx * sy);
    const v2f yy2 = (v2f)(sy * sy);
    const v2f sx2 = (v2f)(sx);
    const v2f sy2 = (v2f)(sy);

    const int pairs = M >> 4;              // 64 pairs per wave chunk
    const v2f* __restrict__ rec = (const v2f*)(pp + 12 * (chunk * pairs));

    v2f acc[4];
    #pragma unroll
    for (int u = 0; u < 4; ++u) acc[u] = (v2f)(0.0f);

    for (int p = 0; p < pairs; p += 8) {
        #pragma unroll
        for (int u = 0; u < 8; ++u) {
            const v2f* r = rec + 6 * (p + u);
            v2f e = r[5];
            e = __builtin_elementwise_fma(r[0], xx2, e);
            e = __builtin_elementwise_fma(r[1], xy2, e);
            e = __builtin_elementwise_fma(r[2], yy2, e);
            e = __builtin_elementwise_fma(r[3], sx2, e);
            e = __builtin_elementwise_fma(r[4], sy2, e);
            v2f ex;
            ex.x = __builtin_amdgcn_exp2f(e.x);
            ex.y = __builtin_amdgcn_exp2f(e.y);
            acc[u & 3] += ex;
        }
    }

    const v2f accv = (acc[0] + acc[1]) + (acc[2] + acc[3]);
    const float accs = accv.x + accv.y;

    __shared__ float psum[8][64];
    psum[chunk][lane_s] = accs;
    __syncthreads();

    if (threadIdx.x < 64) {
        const float tot = ((psum[0][lane_s] + psum[1][lane_s])
                        +  (psum[2][lane_s] + psum[3][lane_s]))
                        + ((psum[4][lane_s] + psum[5][lane_s])
                        +  (psum[6][lane_s] + psum[7][lane_s]));
        float v = -LN2 * __builtin_amdgcn_logf(tot);
        #pragma unroll
        for (int off = 32; off > 0; off >>= 1)
            v += __shfl_down(v, off, 64);
        if (lane_s == 0) atomicAdd(out, v);
    }
}

extern "C" void kernel_launch(void* const* d_in, const int* in_sizes, int n_in,
                              void* d_out, int out_size, void* d_ws, size_t ws_size,
                              hipStream_t stream) {
    const float* sample    = (const float*)d_in[0];
    const float* mu        = (const float*)d_in[1];
    const float* sigma_log = (const float*)d_in[2];
    const float* theta     = (const float*)d_in[3];
    const float* w         = (const float*)d_in[4];
    float* out = (float*)d_out;
    float* pp = (float*)d_ws;

    const int M = in_sizes[3];      // 1024
    const int N = in_sizes[0] / 2;  // 65536

    gm_params<<<1, M, 0, stream>>>(mu, sigma_log, theta, w, pp, out);

    const int grid = N / 64;        // 1024 blocks, 512 threads each
    gm_main<<<grid, 512, 0, stream>>>(sample, pp, out, M);
}